// Round 9
// baseline (156.956 us; speedup 1.0000x reference)
//
#include <hip/hip_runtime.h>

#define NN 8192
#define DD 128
#define CH 16           // column chunks
#define CPC (NN / CH)   // cols per chunk = 512
#define STEPS (CPC / 16)  // 16-candidate steps per chunk = 32

typedef __bf16 bf16x8 __attribute__((ext_vector_type(8)));
typedef float f32x4 __attribute__((ext_vector_type(4)));

#define PACK_INIT __uint_as_float(0x7F7FFFFFu)

// Pack (score, idx): keep high 19 bits of the fp32 score, idx in low 13.
// Monotone bucket-quantization (quantum <= 0.125 for |s|<512); within a
// bucket, smaller idx = smaller float => min-network prefers smaller idx,
// matching reference top_k tie-breaking. Negative scores only occur for
// self (rank-1 by a huge margin), so the inverted idx order there is moot.
static __device__ __forceinline__ float packsi(float s, unsigned idx) {
  return __uint_as_float((__float_as_uint(s) & 0xFFFFE000u) | idx);
}

// Branchless sorted-5 insert (keep 5 smallest): 9 min/max ops, no divergence.
static __device__ __forceinline__ void net5(float& s0, float& s1, float& s2,
                                            float& s3, float& s4, float v) {
  float t1 = fmaxf(s0, v);  s0 = fminf(s0, v);
  float t2 = fmaxf(s1, t1); s1 = fminf(s1, t1);
  float t3 = fmaxf(s2, t2); s2 = fminf(s2, t2);
  float t4 = fmaxf(s3, t3); s3 = fminf(s3, t3);
  s4 = fminf(s4, t4);
}

static __device__ __forceinline__ unsigned short f2bf(float f) {
  unsigned u = __float_as_uint(f);
  u += 0x7FFFu + ((u >> 16) & 1u);   // round-to-nearest-even
  return (unsigned short)(u >> 16);
}

// Kernel 1: f32->bf16 convert, fp32 row sq-norms, zero output scalar.
__global__ __launch_bounds__(256) void prep_kernel(const float* __restrict__ x,
                                                   unsigned short* __restrict__ xb,
                                                   float* __restrict__ sq,
                                                   float* __restrict__ out) {
  const int wave = threadIdx.x >> 6, lane = threadIdx.x & 63;
  const int row = blockIdx.x * 4 + wave;
  const float2 v = ((const float2*)(x + (size_t)row * DD))[lane];
  float ss = v.x * v.x + v.y * v.y;
#pragma unroll
  for (int off = 32; off; off >>= 1) ss += __shfl_down(ss, off);
  if (lane == 0) sq[row] = ss;
  unsigned packed = (unsigned)f2bf(v.x) | ((unsigned)f2bf(v.y) << 16);
  ((unsigned*)(xb + (size_t)row * DD))[lane] = packed;
  if (blockIdx.x == 0 && threadIdx.x == 0) out[0] = 0.0f;
}

// Kernel 2: bf16-MFMA scores + branchless packed top-5 — no LDS, no barriers,
// EXPLICIT depth-2 register pipeline (round-8 failure: compiler kept VGPR=44
// and exposed full L2 latency per step; named X/Y buffers force loads for
// step s+1 in flight while step s computes). R=32 rows/wave; block = 128
// rows x 512 cols; grid (64,16) = 1024 blocks = 4/CU = 4 waves/SIMD.
__global__ __launch_bounds__(256, 4) void dist_topk_kernel(
    const unsigned short* __restrict__ xb, const float* __restrict__ sq,
    float* __restrict__ pscore) {
  const int t = threadIdx.x;
  const int wave = t >> 6, lane = t & 63;
  const int lrow = lane & 15, lquad = lane >> 4;
  const int rowBase = blockIdx.x * 128;
  const int chunk = blockIdx.y;
  const int j0 = chunk * CPC;

  // My-row fragments (MFMA 2nd operand): lane holds X[row][k=lquad*8+j].
  const int myrow0 = rowBase + wave * 32 + lrow;
  const int myrow1 = myrow0 + 16;
  const unsigned short* ap0 = xb + (size_t)myrow0 * DD + lquad * 8;
  const unsigned short* ap1 = xb + (size_t)myrow1 * DD + lquad * 8;
  bf16x8 a00 = *(const bf16x8*)(ap0);
  bf16x8 a01 = *(const bf16x8*)(ap0 + 32);
  bf16x8 a02 = *(const bf16x8*)(ap0 + 64);
  bf16x8 a03 = *(const bf16x8*)(ap0 + 96);
  bf16x8 a10 = *(const bf16x8*)(ap1);
  bf16x8 a11 = *(const bf16x8*)(ap1 + 32);
  bf16x8 a12 = *(const bf16x8*)(ap1 + 64);
  bf16x8 a13 = *(const bf16x8*)(ap1 + 96);

  // Packed sorted-5 lists, one per row group, named scalars.
  float p00 = PACK_INIT, p01 = PACK_INIT, p02 = PACK_INIT, p03 = PACK_INIT,
        p04 = PACK_INIT;
  float p10 = PACK_INIT, p11 = PACK_INIT, p12 = PACK_INIT, p13 = PACK_INIT,
        p14 = PACK_INIT;

  // Candidate fragment base: step S covers rows j0+S*16..+15; this lane
  // loads row (j0+S*16+lrow), k-chunk lquad (matches 1st-operand layout).
  const unsigned short* bbase = xb + (size_t)(j0 + lrow) * DD + lquad * 8;
  const float* sqbase = sq + j0 + lquad * 4;

#define LOADB(B0, B1, B2, B3, SQ4, S)                                          \
  do {                                                                         \
    const unsigned short* bp_ = bbase + (size_t)(S) * (16 * DD);               \
    B0 = *(const bf16x8*)(bp_);                                                \
    B1 = *(const bf16x8*)(bp_ + 32);                                           \
    B2 = *(const bf16x8*)(bp_ + 64);                                           \
    B3 = *(const bf16x8*)(bp_ + 96);                                           \
    SQ4 = *(const f32x4*)(sqbase + (S) * 16);                                  \
  } while (0)

#define STEPC(B0, B1, B2, B3, SQ4, S)                                          \
  do {                                                                         \
    f32x4 acc0 = {0.f, 0.f, 0.f, 0.f};                                         \
    f32x4 acc1 = {0.f, 0.f, 0.f, 0.f};                                         \
    acc0 = __builtin_amdgcn_mfma_f32_16x16x32_bf16(B0, a00, acc0, 0, 0, 0);    \
    acc1 = __builtin_amdgcn_mfma_f32_16x16x32_bf16(B0, a10, acc1, 0, 0, 0);    \
    acc0 = __builtin_amdgcn_mfma_f32_16x16x32_bf16(B1, a01, acc0, 0, 0, 0);    \
    acc1 = __builtin_amdgcn_mfma_f32_16x16x32_bf16(B1, a11, acc1, 0, 0, 0);    \
    acc0 = __builtin_amdgcn_mfma_f32_16x16x32_bf16(B2, a02, acc0, 0, 0, 0);    \
    acc1 = __builtin_amdgcn_mfma_f32_16x16x32_bf16(B2, a12, acc1, 0, 0, 0);    \
    acc0 = __builtin_amdgcn_mfma_f32_16x16x32_bf16(B3, a03, acc0, 0, 0, 0);    \
    acc1 = __builtin_amdgcn_mfma_f32_16x16x32_bf16(B3, a13, acc1, 0, 0, 0);    \
    const unsigned colb_ = (unsigned)(j0 + (S) * 16 + lquad * 4);              \
    net5(p00, p01, p02, p03, p04, packsi(fmaf(-2.0f, acc0[0], SQ4[0]), colb_));     \
    net5(p10, p11, p12, p13, p14, packsi(fmaf(-2.0f, acc1[0], SQ4[0]), colb_));     \
    net5(p00, p01, p02, p03, p04, packsi(fmaf(-2.0f, acc0[1], SQ4[1]), colb_ + 1)); \
    net5(p10, p11, p12, p13, p14, packsi(fmaf(-2.0f, acc1[1], SQ4[1]), colb_ + 1)); \
    net5(p00, p01, p02, p03, p04, packsi(fmaf(-2.0f, acc0[2], SQ4[2]), colb_ + 2)); \
    net5(p10, p11, p12, p13, p14, packsi(fmaf(-2.0f, acc1[2], SQ4[2]), colb_ + 2)); \
    net5(p00, p01, p02, p03, p04, packsi(fmaf(-2.0f, acc0[3], SQ4[3]), colb_ + 3)); \
    net5(p10, p11, p12, p13, p14, packsi(fmaf(-2.0f, acc1[3], SQ4[3]), colb_ + 3)); \
  } while (0)

  bf16x8 xb0, xb1, xb2, xb3;  f32x4 xs;
  bf16x8 yb0, yb1, yb2, yb3;  f32x4 ys;
  LOADB(xb0, xb1, xb2, xb3, xs, 0);
  for (int s = 0; s < STEPS; s += 2) {
    LOADB(yb0, yb1, yb2, yb3, ys, s + 1);
    STEPC(xb0, xb1, xb2, xb3, xs, s);
    const int s2 = (s + 2 < STEPS) ? s + 2 : STEPS - 1;  // clamped dummy on last
    LOADB(xb0, xb1, xb2, xb3, xs, s2);
    STEPC(yb0, yb1, yb2, yb3, ys, s + 1);
  }
#undef LOADB
#undef STEPC

  // Merge across lquads (lanes sharing lrow hold the same two rows).
#pragma unroll
  for (int m = 16; m < 64; m <<= 1) {
    float o0 = __shfl_xor(p00, m), o1 = __shfl_xor(p01, m), o2 = __shfl_xor(p02, m),
          o3 = __shfl_xor(p03, m), o4 = __shfl_xor(p04, m);
    net5(p00, p01, p02, p03, p04, o0);
    net5(p00, p01, p02, p03, p04, o1);
    net5(p00, p01, p02, p03, p04, o2);
    net5(p00, p01, p02, p03, p04, o3);
    net5(p00, p01, p02, p03, p04, o4);
    o0 = __shfl_xor(p10, m); o1 = __shfl_xor(p11, m); o2 = __shfl_xor(p12, m);
    o3 = __shfl_xor(p13, m); o4 = __shfl_xor(p14, m);
    net5(p10, p11, p12, p13, p14, o0);
    net5(p10, p11, p12, p13, p14, o1);
    net5(p10, p11, p12, p13, p14, o2);
    net5(p10, p11, p12, p13, p14, o3);
    net5(p10, p11, p12, p13, p14, o4);
  }
  if (lquad == 0) {
    const size_t b0i = ((size_t)chunk * NN + myrow0) * 5;
    pscore[b0i + 0] = p00; pscore[b0i + 1] = p01; pscore[b0i + 2] = p02;
    pscore[b0i + 3] = p03; pscore[b0i + 4] = p04;
    const size_t b1i = ((size_t)chunk * NN + myrow1) * 5;
    pscore[b1i + 0] = p10; pscore[b1i + 1] = p11; pscore[b1i + 2] = p12;
    pscore[b1i + 3] = p13; pscore[b1i + 4] = p14;
  }
}

// Kernel 3: chunk merge (packed) -> neg idx -> exact fp32 hinge -> atomic mean.
__global__ __launch_bounds__(256) void final_kernel(const float* __restrict__ x,
                                                    const float* __restrict__ pos,
                                                    const float* __restrict__ pscore,
                                                    float* __restrict__ out) {
  const int wave = threadIdx.x >> 6, lane = threadIdx.x & 63;
  const int row = blockIdx.x * 4 + wave;

  float q0 = PACK_INIT, q1 = PACK_INIT, q2 = PACK_INIT, q3 = PACK_INIT,
        q4 = PACK_INIT;
  if (lane < CH) {
    const float* b = pscore + ((size_t)lane * NN + row) * 5;
    q0 = b[0]; q1 = b[1]; q2 = b[2]; q3 = b[3]; q4 = b[4];
  }
#pragma unroll
  for (int m = 1; m < CH; m <<= 1) {
    float o0 = __shfl_xor(q0, m), o1 = __shfl_xor(q1, m), o2 = __shfl_xor(q2, m),
          o3 = __shfl_xor(q3, m), o4 = __shfl_xor(q4, m);
    net5(q0, q1, q2, q3, q4, o0);
    net5(q0, q1, q2, q3, q4, o1);
    net5(q0, q1, q2, q3, q4, o2);
    net5(q0, q1, q2, q3, q4, o3);
    net5(q0, q1, q2, q3, q4, o4);
  }
  const int nidx = (int)(__float_as_uint(__shfl(q4, 0)) & 0x1FFFu);

  const float2 xv  = ((const float2*)(x   + (size_t)row  * DD))[lane];
  const float2 pv  = ((const float2*)(pos + (size_t)row  * DD))[lane];
  const float2 nvv = ((const float2*)(x   + (size_t)nidx * DD))[lane];
  float a0 = xv.x - pv.x + 1e-6f, a1 = xv.y - pv.y + 1e-6f;
  float b0 = xv.x - nvv.x + 1e-6f, b1 = xv.y - nvv.y + 1e-6f;
  float dap = a0 * a0 + a1 * a1;
  float dan = b0 * b0 + b1 * b1;
#pragma unroll
  for (int off = 32; off; off >>= 1) {
    dap += __shfl_down(dap, off);
    dan += __shfl_down(dan, off);
  }
  __shared__ float hs[4];
  if (lane == 0) hs[wave] = fmaxf(sqrtf(dap) - sqrtf(dan) + 0.3f, 0.0f);
  __syncthreads();
  if (threadIdx.x == 0) {
    float s = hs[0] + hs[1] + hs[2] + hs[3];
    atomicAdd(out, s * (1.0f / 8192.0f));
  }
}

extern "C" void kernel_launch(void* const* d_in, const int* in_sizes, int n_in,
                              void* d_out, int out_size, void* d_ws, size_t ws_size,
                              hipStream_t stream) {
  const float* x   = (const float*)d_in[0];
  const float* pos = (const float*)d_in[1];
  float* out = (float*)d_out;

  char* w = (char*)d_ws;
  unsigned short* xb = (unsigned short*)w;                       // 2 MB
  float* sq = (float*)(w + (size_t)NN * DD * 2);                 // 32 KB
  float* pscore = (float*)(w + (size_t)NN * DD * 2 + (size_t)NN * 4);  // 2.62 MB

  prep_kernel<<<NN / 4, 256, 0, stream>>>(x, xb, sq, out);
  dist_topk_kernel<<<dim3(NN / 128, CH), 256, 0, stream>>>(xb, sq, pscore);
  final_kernel<<<NN / 4, 256, 0, stream>>>(x, pos, pscore, out);
}

// Round 10
// 124.186 us; speedup vs baseline: 1.2639x; 1.2639x over previous
//
#include <hip/hip_runtime.h>

#define NN 8192
#define DD 128
#define CH 16           // column chunks
#define CPC (NN / CH)   // cols per chunk = 512
#define TILES (CPC / 64)

typedef __bf16 bf16x8 __attribute__((ext_vector_type(8)));
typedef float f32x4 __attribute__((ext_vector_type(4)));

#define PACK_INIT __uint_as_float(0x7F7FFFFFu)

// Pack (score, idx): high 19 bits of fp32 score, idx in low 13.
// Monotone bucket-quantization (quantum <= 0.125 for |s|<512); within a
// bucket smaller idx = smaller float => min-network tie-breaks to smaller
// idx, matching reference top_k. (absmax 0.0 in rounds 6-9.)
static __device__ __forceinline__ float packsi(float s, unsigned idx) {
  return __uint_as_float((__float_as_uint(s) & 0xFFFFE000u) | idx);
}

// Branchless keep-4-smallest (off-diagonal blocks: self absent, negative =
// 4th-smallest non-self) and keep-5-smallest (diagonal blocks: self included).
#define NET4(S0, S1, S2, S3, v)                                                \
  {                                                                            \
    float v_ = (v);                                                            \
    float t1 = fmaxf(S0, v_); S0 = fminf(S0, v_);                              \
    float t2 = fmaxf(S1, t1); S1 = fminf(S1, t1);                              \
    float t3 = fmaxf(S2, t2); S2 = fminf(S2, t2);                              \
    S3 = fminf(S3, t3);                                                        \
  }
#define NET5(S0, S1, S2, S3, S4, v)                                            \
  {                                                                            \
    float v_ = (v);                                                            \
    float t1 = fmaxf(S0, v_); S0 = fminf(S0, v_);                              \
    float t2 = fmaxf(S1, t1); S1 = fminf(S1, t1);                              \
    float t3 = fmaxf(S2, t2); S2 = fminf(S2, t2);                              \
    float t4 = fmaxf(S3, t3); S3 = fminf(S3, t3);                              \
    S4 = fminf(S4, t4);                                                        \
  }

static __device__ __forceinline__ unsigned short f2bf(float f) {
  unsigned u = __float_as_uint(f);
  u += 0x7FFFu + ((u >> 16) & 1u);   // round-to-nearest-even
  return (unsigned short)(u >> 16);
}

// Kernel 1: f32->bf16 convert, fp32 row sq-norms, zero output scalar.
__global__ __launch_bounds__(256) void prep_kernel(const float* __restrict__ x,
                                                   unsigned short* __restrict__ xb,
                                                   float* __restrict__ sq,
                                                   float* __restrict__ out) {
  const int wave = threadIdx.x >> 6, lane = threadIdx.x & 63;
  const int row = blockIdx.x * 4 + wave;
  const float2 v = ((const float2*)(x + (size_t)row * DD))[lane];
  float ss = v.x * v.x + v.y * v.y;
#pragma unroll
  for (int off = 32; off; off >>= 1) ss += __shfl_down(ss, off);
  if (lane == 0) sq[row] = ss;
  unsigned packed = (unsigned)f2bf(v.x) | ((unsigned)f2bf(v.y) << 16);
  ((unsigned*)(xb + (size_t)row * DD))[lane] = packed;
  if (blockIdx.x == 0 && threadIdx.x == 0) out[0] = 0.0f;
}

// Kernel 2: LDS-staged bf16-MFMA scores + branchless packed top-k.
// 64 rows/wave (4 row-groups of 16 share every B fragment -> LDS/pair
// halved vs round 6). Block = 256 rows x 512 cols; grid (32,16) = 512
// blocks = 2/CU (round 6: sufficient for this structure). Off-diagonal
// blocks keep top-4 (net4); only diagonal blocks (bx>>1==by, self present)
// keep top-5. Unused 5th slot stays PACK_INIT = list padding for merge.
__global__ __launch_bounds__(256, 2) void dist_topk_kernel(
    const unsigned short* __restrict__ xb, const float* __restrict__ sq,
    float* __restrict__ pscore) {
  const int t = threadIdx.x;
  const int wave = t >> 6, lane = t & 63;
  const int lrow = lane & 15, lquad = lane >> 4;
  const int rowBase = blockIdx.x * 256;
  const int chunk = blockIdx.y;
  const int j0 = chunk * CPC;
  const bool hasDiag = ((blockIdx.x >> 1) == (int)blockIdx.y);

  __shared__ unsigned short colsB[2][64 * DD];   // 2 x 16 KB, XOR-swizzled
  __shared__ float sqs[2][64];

  // A fragments for 4 row-groups: lane holds X[row][k=lquad*8+j].
  const int r0 = rowBase + wave * 64 + lrow;     // group g row = r0 + g*16
  const unsigned short* ap0 = xb + (size_t)(r0)*DD + lquad * 8;
  const unsigned short* ap1 = xb + (size_t)(r0 + 16) * DD + lquad * 8;
  const unsigned short* ap2 = xb + (size_t)(r0 + 32) * DD + lquad * 8;
  const unsigned short* ap3 = xb + (size_t)(r0 + 48) * DD + lquad * 8;
  bf16x8 a00 = *(const bf16x8*)(ap0), a01 = *(const bf16x8*)(ap0 + 32),
         a02 = *(const bf16x8*)(ap0 + 64), a03 = *(const bf16x8*)(ap0 + 96);
  bf16x8 a10 = *(const bf16x8*)(ap1), a11 = *(const bf16x8*)(ap1 + 32),
         a12 = *(const bf16x8*)(ap1 + 64), a13 = *(const bf16x8*)(ap1 + 96);
  bf16x8 a20 = *(const bf16x8*)(ap2), a21 = *(const bf16x8*)(ap2 + 32),
         a22 = *(const bf16x8*)(ap2 + 64), a23 = *(const bf16x8*)(ap2 + 96);
  bf16x8 a30 = *(const bf16x8*)(ap3), a31 = *(const bf16x8*)(ap3 + 32),
         a32 = *(const bf16x8*)(ap3 + 64), a33 = *(const bf16x8*)(ap3 + 96);

  // Packed sorted lists, one per row-group, named scalars.
  float q00 = PACK_INIT, q01 = PACK_INIT, q02 = PACK_INIT, q03 = PACK_INIT,
        q04 = PACK_INIT;
  float q10 = PACK_INIT, q11 = PACK_INIT, q12 = PACK_INIT, q13 = PACK_INIT,
        q14 = PACK_INIT;
  float q20 = PACK_INIT, q21 = PACK_INIT, q22 = PACK_INIT, q23 = PACK_INIT,
        q24 = PACK_INIT;
  float q30 = PACK_INIT, q31 = PACK_INIT, q32 = PACK_INIT, q33 = PACK_INIT,
        q34 = PACK_INIT;

  // Staging closed-form swizzle (round-5 verified).
  const int sr = t >> 4, sch = t & 15;
  const int dst0 = (sr << 4) | (sch ^ (sr & 15));

  const float4* srcv = (const float4*)(xb + (size_t)j0 * DD);
  float4 g0 = srcv[t], g1 = srcv[t + 256], g2 = srcv[t + 512], g3 = srcv[t + 768];
  float sqv = 0.0f;
  if (t < 64) sqv = sq[j0 + t];

#define KBODY(INSROW)                                                          \
  for (int it = 0; it < TILES; ++it) {                                         \
    const int jt = j0 + it * 64;                                               \
    const int cur = it & 1;                                                    \
    {                                                                          \
      float4* dstv = (float4*)colsB[cur];                                      \
      dstv[dst0] = g0;                                                         \
      dstv[dst0 + 256] = g1;                                                   \
      dstv[dst0 + 512] = g2;                                                   \
      dstv[dst0 + 768] = g3;                                                   \
      if (t < 64) sqs[cur][t] = sqv;                                           \
    }                                                                          \
    if (it + 1 < TILES) {                                                      \
      const float4* nsrc = (const float4*)(xb + (size_t)(jt + 64) * DD);       \
      g0 = nsrc[t]; g1 = nsrc[t + 256]; g2 = nsrc[t + 512]; g3 = nsrc[t + 768];\
      if (t < 64) sqv = sq[jt + 64 + t];                                       \
    }                                                                          \
    __syncthreads();                                                           \
    _Pragma("unroll")                                                          \
    for (int ct = 0; ct < 4; ++ct) {                                           \
      const unsigned short* bb = &colsB[cur][(ct * 16 + lrow) * DD];           \
      bf16x8 b0 = *(const bf16x8*)(bb + (((0 + lquad) ^ lrow) << 3));          \
      bf16x8 b1 = *(const bf16x8*)(bb + (((4 + lquad) ^ lrow) << 3));          \
      bf16x8 b2 = *(const bf16x8*)(bb + (((8 + lquad) ^ lrow) << 3));          \
      bf16x8 b3 = *(const bf16x8*)(bb + (((12 + lquad) ^ lrow) << 3));         \
      f32x4 ac0 = {0.f, 0.f, 0.f, 0.f}, ac1 = {0.f, 0.f, 0.f, 0.f};           \
      f32x4 ac2 = {0.f, 0.f, 0.f, 0.f}, ac3 = {0.f, 0.f, 0.f, 0.f};           \
      ac0 = __builtin_amdgcn_mfma_f32_16x16x32_bf16(b0, a00, ac0, 0, 0, 0);    \
      ac1 = __builtin_amdgcn_mfma_f32_16x16x32_bf16(b0, a10, ac1, 0, 0, 0);    \
      ac2 = __builtin_amdgcn_mfma_f32_16x16x32_bf16(b0, a20, ac2, 0, 0, 0);    \
      ac3 = __builtin_amdgcn_mfma_f32_16x16x32_bf16(b0, a30, ac3, 0, 0, 0);    \
      ac0 = __builtin_amdgcn_mfma_f32_16x16x32_bf16(b1, a01, ac0, 0, 0, 0);    \
      ac1 = __builtin_amdgcn_mfma_f32_16x16x32_bf16(b1, a11, ac1, 0, 0, 0);    \
      ac2 = __builtin_amdgcn_mfma_f32_16x16x32_bf16(b1, a21, ac2, 0, 0, 0);    \
      ac3 = __builtin_amdgcn_mfma_f32_16x16x32_bf16(b1, a31, ac3, 0, 0, 0);    \
      ac0 = __builtin_amdgcn_mfma_f32_16x16x32_bf16(b2, a02, ac0, 0, 0, 0);    \
      ac1 = __builtin_amdgcn_mfma_f32_16x16x32_bf16(b2, a12, ac1, 0, 0, 0);    \
      ac2 = __builtin_amdgcn_mfma_f32_16x16x32_bf16(b2, a22, ac2, 0, 0, 0);    \
      ac3 = __builtin_amdgcn_mfma_f32_16x16x32_bf16(b2, a32, ac3, 0, 0, 0);    \
      ac0 = __builtin_amdgcn_mfma_f32_16x16x32_bf16(b3, a03, ac0, 0, 0, 0);    \
      ac1 = __builtin_amdgcn_mfma_f32_16x16x32_bf16(b3, a13, ac1, 0, 0, 0);    \
      ac2 = __builtin_amdgcn_mfma_f32_16x16x32_bf16(b3, a23, ac2, 0, 0, 0);    \
      ac3 = __builtin_amdgcn_mfma_f32_16x16x32_bf16(b3, a33, ac3, 0, 0, 0);    \
      const f32x4 sq4 = *(const f32x4*)&sqs[cur][ct * 16 + lquad * 4];         \
      const unsigned colb = (unsigned)(jt + ct * 16 + lquad * 4);              \
      _Pragma("unroll")                                                        \
      for (int r = 0; r < 4; ++r) {                                            \
        INSROW(0, packsi(fmaf(-2.0f, ac0[r], sq4[r]), colb + r));              \
        INSROW(1, packsi(fmaf(-2.0f, ac1[r], sq4[r]), colb + r));              \
        INSROW(2, packsi(fmaf(-2.0f, ac2[r], sq4[r]), colb + r));              \
        INSROW(3, packsi(fmaf(-2.0f, ac3[r], sq4[r]), colb + r));              \
      }                                                                        \
    }                                                                          \
  }

#define INS4(G, V) NET4(q##G##0, q##G##1, q##G##2, q##G##3, (V))
#define INS5(G, V) NET5(q##G##0, q##G##1, q##G##2, q##G##3, q##G##4, (V))

  if (hasDiag) {
    KBODY(INS5)
  } else {
    KBODY(INS4)
  }
#undef KBODY

  // Merge across lquads (lanes sharing lrow hold the same 4 rows).
#define MERGE4(G, M)                                                           \
  {                                                                            \
    float o0 = __shfl_xor(q##G##0, M), o1 = __shfl_xor(q##G##1, M),            \
          o2 = __shfl_xor(q##G##2, M), o3 = __shfl_xor(q##G##3, M);            \
    NET4(q##G##0, q##G##1, q##G##2, q##G##3, o0);                              \
    NET4(q##G##0, q##G##1, q##G##2, q##G##3, o1);                              \
    NET4(q##G##0, q##G##1, q##G##2, q##G##3, o2);                              \
    NET4(q##G##0, q##G##1, q##G##2, q##G##3, o3);                              \
  }
#define MERGE5(G, M)                                                           \
  {                                                                            \
    float o0 = __shfl_xor(q##G##0, M), o1 = __shfl_xor(q##G##1, M),            \
          o2 = __shfl_xor(q##G##2, M), o3 = __shfl_xor(q##G##3, M),            \
          o4 = __shfl_xor(q##G##4, M);                                         \
    NET5(q##G##0, q##G##1, q##G##2, q##G##3, q##G##4, o0);                     \
    NET5(q##G##0, q##G##1, q##G##2, q##G##3, q##G##4, o1);                     \
    NET5(q##G##0, q##G##1, q##G##2, q##G##3, q##G##4, o2);                     \
    NET5(q##G##0, q##G##1, q##G##2, q##G##3, q##G##4, o3);                     \
    NET5(q##G##0, q##G##1, q##G##2, q##G##3, q##G##4, o4);                     \
  }
  if (hasDiag) {
    MERGE5(0, 16) MERGE5(1, 16) MERGE5(2, 16) MERGE5(3, 16)
    MERGE5(0, 32) MERGE5(1, 32) MERGE5(2, 32) MERGE5(3, 32)
  } else {
    MERGE4(0, 16) MERGE4(1, 16) MERGE4(2, 16) MERGE4(3, 16)
    MERGE4(0, 32) MERGE4(1, 32) MERGE4(2, 32) MERGE4(3, 32)
  }

  if (lquad == 0) {
    // pscore layout: [row][CH*5] -> coalesced per-row read in final_kernel.
    float* b0p = pscore + (size_t)(r0)*80 + chunk * 5;
    b0p[0] = q00; b0p[1] = q01; b0p[2] = q02; b0p[3] = q03; b0p[4] = q04;
    float* b1p = pscore + (size_t)(r0 + 16) * 80 + chunk * 5;
    b1p[0] = q10; b1p[1] = q11; b1p[2] = q12; b1p[3] = q13; b1p[4] = q14;
    float* b2p = pscore + (size_t)(r0 + 32) * 80 + chunk * 5;
    b2p[0] = q20; b2p[1] = q21; b2p[2] = q22; b2p[3] = q23; b2p[4] = q24;
    float* b3p = pscore + (size_t)(r0 + 48) * 80 + chunk * 5;
    b3p[0] = q30; b3p[1] = q31; b3p[2] = q32; b3p[3] = q33; b3p[4] = q34;
  }
}

// Kernel 3: chunk merge (packed) -> neg idx -> exact fp32 hinge -> atomic mean.
__global__ __launch_bounds__(256) void final_kernel(const float* __restrict__ x,
                                                    const float* __restrict__ pos,
                                                    const float* __restrict__ pscore,
                                                    float* __restrict__ out) {
  const int wave = threadIdx.x >> 6, lane = threadIdx.x & 63;
  const int row = blockIdx.x * 4 + wave;

  float q0 = PACK_INIT, q1 = PACK_INIT, q2 = PACK_INIT, q3 = PACK_INIT,
        q4 = PACK_INIT;
  if (lane < CH) {
    const float* b = pscore + (size_t)row * 80 + lane * 5;   // contiguous row
    q0 = b[0]; q1 = b[1]; q2 = b[2]; q3 = b[3]; q4 = b[4];
  }
#pragma unroll
  for (int m = 1; m < CH; m <<= 1) {
    float o0 = __shfl_xor(q0, m), o1 = __shfl_xor(q1, m), o2 = __shfl_xor(q2, m),
          o3 = __shfl_xor(q3, m), o4 = __shfl_xor(q4, m);
    NET5(q0, q1, q2, q3, q4, o0);
    NET5(q0, q1, q2, q3, q4, o1);
    NET5(q0, q1, q2, q3, q4, o2);
    NET5(q0, q1, q2, q3, q4, o3);
    NET5(q0, q1, q2, q3, q4, o4);
  }
  const int nidx = (int)(__float_as_uint(__shfl(q4, 0)) & 0x1FFFu);

  const float2 xv  = ((const float2*)(x   + (size_t)row  * DD))[lane];
  const float2 pv  = ((const float2*)(pos + (size_t)row  * DD))[lane];
  const float2 nvv = ((const float2*)(x   + (size_t)nidx * DD))[lane];
  float a0 = xv.x - pv.x + 1e-6f, a1 = xv.y - pv.y + 1e-6f;
  float b0 = xv.x - nvv.x + 1e-6f, b1 = xv.y - nvv.y + 1e-6f;
  float dap = a0 * a0 + a1 * a1;
  float dan = b0 * b0 + b1 * b1;
#pragma unroll
  for (int off = 32; off; off >>= 1) {
    dap += __shfl_down(dap, off);
    dan += __shfl_down(dan, off);
  }
  __shared__ float hs[4];
  if (lane == 0) hs[wave] = fmaxf(sqrtf(dap) - sqrtf(dan) + 0.3f, 0.0f);
  __syncthreads();
  if (threadIdx.x == 0) {
    float s = hs[0] + hs[1] + hs[2] + hs[3];
    atomicAdd(out, s * (1.0f / 8192.0f));
  }
}

extern "C" void kernel_launch(void* const* d_in, const int* in_sizes, int n_in,
                              void* d_out, int out_size, void* d_ws, size_t ws_size,
                              hipStream_t stream) {
  const float* x   = (const float*)d_in[0];
  const float* pos = (const float*)d_in[1];
  float* out = (float*)d_out;

  char* w = (char*)d_ws;
  unsigned short* xb = (unsigned short*)w;                       // 2 MB
  float* sq = (float*)(w + (size_t)NN * DD * 2);                 // 32 KB
  float* pscore = (float*)(w + (size_t)NN * DD * 2 + (size_t)NN * 4);  // 2.62 MB

  prep_kernel<<<NN / 4, 256, 0, stream>>>(x, xb, sq, out);
  dist_topk_kernel<<<dim3(NN / 256, CH), 256, 0, stream>>>(xb, sq, pscore);
  final_kernel<<<NN / 4, 256, 0, stream>>>(x, pos, pscore, out);
}

// Round 11
// 105.916 us; speedup vs baseline: 1.4819x; 1.1725x over previous
//
#include <hip/hip_runtime.h>

#define NN 8192
#define DD 128
#define CH 16           // column chunks
#define CPC (NN / CH)   // cols per chunk = 512
#define TILES (CPC / 64)
#define NPART 64        // partial-sum bins

typedef __bf16 bf16x8 __attribute__((ext_vector_type(8)));
typedef float f32x4 __attribute__((ext_vector_type(4)));

#define PACK_INIT __uint_as_float(0x7F7FFFFFu)

// Pack (score, idx): high 19 bits of fp32 score, idx in low 13 (round 5-10,
// absmax 0.0 throughout).
static __device__ __forceinline__ float packsi(float s, unsigned idx) {
  return __uint_as_float((__float_as_uint(s) & 0xFFFFE000u) | idx);
}

// Sorted-insert via med3: closed form sk' = med3(v, s[k-1], sk), s0' = min.
// 5 ops (NET5) / 4 ops (NET4), dependency depth 1 (vs 9/7 ops depth 5 of the
// min/max network) — v_med3_f32 is full-rate VOP3.
#define NET4(S0, S1, S2, S3, v)                                                \
  {                                                                            \
    float v_ = (v), o0 = S0, o1 = S1, o2 = S2;                                 \
    S0 = fminf(o0, v_);                                                        \
    S1 = __builtin_amdgcn_fmed3f(v_, o0, o1);                                  \
    S2 = __builtin_amdgcn_fmed3f(v_, o1, o2);                                  \
    S3 = __builtin_amdgcn_fmed3f(v_, o2, S3);                                  \
  }
#define NET5(S0, S1, S2, S3, S4, v)                                            \
  {                                                                            \
    float v_ = (v), o0 = S0, o1 = S1, o2 = S2, o3 = S3;                        \
    S0 = fminf(o0, v_);                                                        \
    S1 = __builtin_amdgcn_fmed3f(v_, o0, o1);                                  \
    S2 = __builtin_amdgcn_fmed3f(v_, o1, o2);                                  \
    S3 = __builtin_amdgcn_fmed3f(v_, o2, o3);                                  \
    S4 = __builtin_amdgcn_fmed3f(v_, o3, S4);                                  \
  }

static __device__ __forceinline__ unsigned short f2bf(float f) {
  unsigned u = __float_as_uint(f);
  u += 0x7FFFu + ((u >> 16) & 1u);   // round-to-nearest-even
  return (unsigned short)(u >> 16);
}

// Kernel 1: f32->bf16 convert, fp32 row sq-norms, zero partial bins.
__global__ __launch_bounds__(256) void prep_kernel(const float* __restrict__ x,
                                                   unsigned short* __restrict__ xb,
                                                   float* __restrict__ sq,
                                                   float* __restrict__ partial) {
  const int wave = threadIdx.x >> 6, lane = threadIdx.x & 63;
  const int row = blockIdx.x * 4 + wave;
  const float2 v = ((const float2*)(x + (size_t)row * DD))[lane];
  float ss = v.x * v.x + v.y * v.y;
#pragma unroll
  for (int off = 32; off; off >>= 1) ss += __shfl_down(ss, off);
  if (lane == 0) sq[row] = ss;
  unsigned packed = (unsigned)f2bf(v.x) | ((unsigned)f2bf(v.y) << 16);
  ((unsigned*)(xb + (size_t)row * DD))[lane] = packed;
  if (blockIdx.x == 0 && threadIdx.x < NPART) partial[threadIdx.x] = 0.0f;
}

// Kernel 2: LDS-staged bf16-MFMA scores + med3 packed top-k.
// 64 rows/wave (4 row-groups of 16 share every B fragment). Block = 256 rows
// x 512 cols; grid (32,16) = 512 blocks = 2/CU. Off-diagonal blocks keep
// top-4 (self absent); diagonal blocks (bx>>1==by) keep top-5.
__global__ __launch_bounds__(256, 2) void dist_topk_kernel(
    const unsigned short* __restrict__ xb, const float* __restrict__ sq,
    float* __restrict__ pscore) {
  const int t = threadIdx.x;
  const int wave = t >> 6, lane = t & 63;
  const int lrow = lane & 15, lquad = lane >> 4;
  const int rowBase = blockIdx.x * 256;
  const int chunk = blockIdx.y;
  const int j0 = chunk * CPC;
  const bool hasDiag = ((blockIdx.x >> 1) == (int)blockIdx.y);

  __shared__ unsigned short colsB[2][64 * DD];   // 2 x 16 KB, XOR-swizzled
  __shared__ float sqs[2][64];

  // A fragments for 4 row-groups: lane holds X[row][k=lquad*8+j].
  const int r0 = rowBase + wave * 64 + lrow;     // group g row = r0 + g*16
  const unsigned short* ap0 = xb + (size_t)(r0)*DD + lquad * 8;
  const unsigned short* ap1 = xb + (size_t)(r0 + 16) * DD + lquad * 8;
  const unsigned short* ap2 = xb + (size_t)(r0 + 32) * DD + lquad * 8;
  const unsigned short* ap3 = xb + (size_t)(r0 + 48) * DD + lquad * 8;
  bf16x8 a00 = *(const bf16x8*)(ap0), a01 = *(const bf16x8*)(ap0 + 32),
         a02 = *(const bf16x8*)(ap0 + 64), a03 = *(const bf16x8*)(ap0 + 96);
  bf16x8 a10 = *(const bf16x8*)(ap1), a11 = *(const bf16x8*)(ap1 + 32),
         a12 = *(const bf16x8*)(ap1 + 64), a13 = *(const bf16x8*)(ap1 + 96);
  bf16x8 a20 = *(const bf16x8*)(ap2), a21 = *(const bf16x8*)(ap2 + 32),
         a22 = *(const bf16x8*)(ap2 + 64), a23 = *(const bf16x8*)(ap2 + 96);
  bf16x8 a30 = *(const bf16x8*)(ap3), a31 = *(const bf16x8*)(ap3 + 32),
         a32 = *(const bf16x8*)(ap3 + 64), a33 = *(const bf16x8*)(ap3 + 96);

  // Packed sorted lists, one per row-group, named scalars.
  float q00 = PACK_INIT, q01 = PACK_INIT, q02 = PACK_INIT, q03 = PACK_INIT,
        q04 = PACK_INIT;
  float q10 = PACK_INIT, q11 = PACK_INIT, q12 = PACK_INIT, q13 = PACK_INIT,
        q14 = PACK_INIT;
  float q20 = PACK_INIT, q21 = PACK_INIT, q22 = PACK_INIT, q23 = PACK_INIT,
        q24 = PACK_INIT;
  float q30 = PACK_INIT, q31 = PACK_INIT, q32 = PACK_INIT, q33 = PACK_INIT,
        q34 = PACK_INIT;

  // Staging closed-form swizzle (round-5 verified).
  const int sr = t >> 4, sch = t & 15;
  const int dst0 = (sr << 4) | (sch ^ (sr & 15));

  const float4* srcv = (const float4*)(xb + (size_t)j0 * DD);
  float4 g0 = srcv[t], g1 = srcv[t + 256], g2 = srcv[t + 512], g3 = srcv[t + 768];
  float sqv = 0.0f;
  if (t < 64) sqv = sq[j0 + t];

#define KBODY(INSROW)                                                          \
  for (int it = 0; it < TILES; ++it) {                                         \
    const int jt = j0 + it * 64;                                               \
    const int cur = it & 1;                                                    \
    {                                                                          \
      float4* dstv = (float4*)colsB[cur];                                      \
      dstv[dst0] = g0;                                                         \
      dstv[dst0 + 256] = g1;                                                   \
      dstv[dst0 + 512] = g2;                                                   \
      dstv[dst0 + 768] = g3;                                                   \
      if (t < 64) sqs[cur][t] = sqv;                                           \
    }                                                                          \
    if (it + 1 < TILES) {                                                      \
      const float4* nsrc = (const float4*)(xb + (size_t)(jt + 64) * DD);       \
      g0 = nsrc[t]; g1 = nsrc[t + 256]; g2 = nsrc[t + 512]; g3 = nsrc[t + 768];\
      if (t < 64) sqv = sq[jt + 64 + t];                                       \
    }                                                                          \
    __syncthreads();                                                           \
    _Pragma("unroll")                                                          \
    for (int ct = 0; ct < 4; ++ct) {                                           \
      const unsigned short* bb = &colsB[cur][(ct * 16 + lrow) * DD];           \
      bf16x8 b0 = *(const bf16x8*)(bb + (((0 + lquad) ^ lrow) << 3));          \
      bf16x8 b1 = *(const bf16x8*)(bb + (((4 + lquad) ^ lrow) << 3));          \
      bf16x8 b2 = *(const bf16x8*)(bb + (((8 + lquad) ^ lrow) << 3));          \
      bf16x8 b3 = *(const bf16x8*)(bb + (((12 + lquad) ^ lrow) << 3));         \
      f32x4 ac0 = {0.f, 0.f, 0.f, 0.f}, ac1 = {0.f, 0.f, 0.f, 0.f};           \
      f32x4 ac2 = {0.f, 0.f, 0.f, 0.f}, ac3 = {0.f, 0.f, 0.f, 0.f};           \
      ac0 = __builtin_amdgcn_mfma_f32_16x16x32_bf16(b0, a00, ac0, 0, 0, 0);    \
      ac1 = __builtin_amdgcn_mfma_f32_16x16x32_bf16(b0, a10, ac1, 0, 0, 0);    \
      ac2 = __builtin_amdgcn_mfma_f32_16x16x32_bf16(b0, a20, ac2, 0, 0, 0);    \
      ac3 = __builtin_amdgcn_mfma_f32_16x16x32_bf16(b0, a30, ac3, 0, 0, 0);    \
      ac0 = __builtin_amdgcn_mfma_f32_16x16x32_bf16(b1, a01, ac0, 0, 0, 0);    \
      ac1 = __builtin_amdgcn_mfma_f32_16x16x32_bf16(b1, a11, ac1, 0, 0, 0);    \
      ac2 = __builtin_amdgcn_mfma_f32_16x16x32_bf16(b1, a21, ac2, 0, 0, 0);    \
      ac3 = __builtin_amdgcn_mfma_f32_16x16x32_bf16(b1, a31, ac3, 0, 0, 0);    \
      ac0 = __builtin_amdgcn_mfma_f32_16x16x32_bf16(b2, a02, ac0, 0, 0, 0);    \
      ac1 = __builtin_amdgcn_mfma_f32_16x16x32_bf16(b2, a12, ac1, 0, 0, 0);    \
      ac2 = __builtin_amdgcn_mfma_f32_16x16x32_bf16(b2, a22, ac2, 0, 0, 0);    \
      ac3 = __builtin_amdgcn_mfma_f32_16x16x32_bf16(b2, a32, ac3, 0, 0, 0);    \
      ac0 = __builtin_amdgcn_mfma_f32_16x16x32_bf16(b3, a03, ac0, 0, 0, 0);    \
      ac1 = __builtin_amdgcn_mfma_f32_16x16x32_bf16(b3, a13, ac1, 0, 0, 0);    \
      ac2 = __builtin_amdgcn_mfma_f32_16x16x32_bf16(b3, a23, ac2, 0, 0, 0);    \
      ac3 = __builtin_amdgcn_mfma_f32_16x16x32_bf16(b3, a33, ac3, 0, 0, 0);    \
      const f32x4 sq4 = *(const f32x4*)&sqs[cur][ct * 16 + lquad * 4];         \
      const unsigned colb = (unsigned)(jt + ct * 16 + lquad * 4);              \
      _Pragma("unroll")                                                        \
      for (int r = 0; r < 4; ++r) {                                            \
        INSROW(0, packsi(fmaf(-2.0f, ac0[r], sq4[r]), colb + r));              \
        INSROW(1, packsi(fmaf(-2.0f, ac1[r], sq4[r]), colb + r));              \
        INSROW(2, packsi(fmaf(-2.0f, ac2[r], sq4[r]), colb + r));              \
        INSROW(3, packsi(fmaf(-2.0f, ac3[r], sq4[r]), colb + r));              \
      }                                                                        \
    }                                                                          \
  }

#define INS4(G, V) NET4(q##G##0, q##G##1, q##G##2, q##G##3, (V))
#define INS5(G, V) NET5(q##G##0, q##G##1, q##G##2, q##G##3, q##G##4, (V))

  if (hasDiag) {
    KBODY(INS5)
  } else {
    KBODY(INS4)
  }
#undef KBODY

  // Merge across lquads (lanes sharing lrow hold the same 4 rows).
#define MERGE4(G, M)                                                           \
  {                                                                            \
    float o0 = __shfl_xor(q##G##0, M), o1 = __shfl_xor(q##G##1, M),            \
          o2 = __shfl_xor(q##G##2, M), o3 = __shfl_xor(q##G##3, M);            \
    NET4(q##G##0, q##G##1, q##G##2, q##G##3, o0);                              \
    NET4(q##G##0, q##G##1, q##G##2, q##G##3, o1);                              \
    NET4(q##G##0, q##G##1, q##G##2, q##G##3, o2);                              \
    NET4(q##G##0, q##G##1, q##G##2, q##G##3, o3);                              \
  }
#define MERGE5(G, M)                                                           \
  {                                                                            \
    float o0 = __shfl_xor(q##G##0, M), o1 = __shfl_xor(q##G##1, M),            \
          o2 = __shfl_xor(q##G##2, M), o3 = __shfl_xor(q##G##3, M),            \
          o4 = __shfl_xor(q##G##4, M);                                         \
    NET5(q##G##0, q##G##1, q##G##2, q##G##3, q##G##4, o0);                     \
    NET5(q##G##0, q##G##1, q##G##2, q##G##3, q##G##4, o1);                     \
    NET5(q##G##0, q##G##1, q##G##2, q##G##3, q##G##4, o2);                     \
    NET5(q##G##0, q##G##1, q##G##2, q##G##3, q##G##4, o3);                     \
    NET5(q##G##0, q##G##1, q##G##2, q##G##3, q##G##4, o4);                     \
  }
  if (hasDiag) {
    MERGE5(0, 16) MERGE5(1, 16) MERGE5(2, 16) MERGE5(3, 16)
    MERGE5(0, 32) MERGE5(1, 32) MERGE5(2, 32) MERGE5(3, 32)
  } else {
    MERGE4(0, 16) MERGE4(1, 16) MERGE4(2, 16) MERGE4(3, 16)
    MERGE4(0, 32) MERGE4(1, 32) MERGE4(2, 32) MERGE4(3, 32)
  }

  if (lquad == 0) {
    // pscore layout: [row][CH*5] -> coalesced per-row read in final_kernel.
    float* b0p = pscore + (size_t)(r0)*80 + chunk * 5;
    b0p[0] = q00; b0p[1] = q01; b0p[2] = q02; b0p[3] = q03; b0p[4] = q04;
    float* b1p = pscore + (size_t)(r0 + 16) * 80 + chunk * 5;
    b1p[0] = q10; b1p[1] = q11; b1p[2] = q12; b1p[3] = q13; b1p[4] = q14;
    float* b2p = pscore + (size_t)(r0 + 32) * 80 + chunk * 5;
    b2p[0] = q20; b2p[1] = q21; b2p[2] = q22; b2p[3] = q23; b2p[4] = q24;
    float* b3p = pscore + (size_t)(r0 + 48) * 80 + chunk * 5;
    b3p[0] = q30; b3p[1] = q31; b3p[2] = q32; b3p[3] = q33; b3p[4] = q34;
  }
}

// Kernel 3: chunk merge (packed) -> neg idx -> exact fp32 hinge -> 64 bins
// (round-6 lesson in reverse: 2048 same-address atomics cost ~10 us; bins
// parallelize the serialization).
__global__ __launch_bounds__(256) void final_kernel(const float* __restrict__ x,
                                                    const float* __restrict__ pos,
                                                    const float* __restrict__ pscore,
                                                    float* __restrict__ partial) {
  const int wave = threadIdx.x >> 6, lane = threadIdx.x & 63;
  const int row = blockIdx.x * 4 + wave;

  float q0 = PACK_INIT, q1 = PACK_INIT, q2 = PACK_INIT, q3 = PACK_INIT,
        q4 = PACK_INIT;
  if (lane < CH) {
    const float* b = pscore + (size_t)row * 80 + lane * 5;   // contiguous row
    q0 = b[0]; q1 = b[1]; q2 = b[2]; q3 = b[3]; q4 = b[4];
  }
#pragma unroll
  for (int m = 1; m < CH; m <<= 1) {
    float o0 = __shfl_xor(q0, m), o1 = __shfl_xor(q1, m), o2 = __shfl_xor(q2, m),
          o3 = __shfl_xor(q3, m), o4 = __shfl_xor(q4, m);
    NET5(q0, q1, q2, q3, q4, o0);
    NET5(q0, q1, q2, q3, q4, o1);
    NET5(q0, q1, q2, q3, q4, o2);
    NET5(q0, q1, q2, q3, q4, o3);
    NET5(q0, q1, q2, q3, q4, o4);
  }
  const int nidx = (int)(__float_as_uint(__shfl(q4, 0)) & 0x1FFFu);

  const float2 xv  = ((const float2*)(x   + (size_t)row  * DD))[lane];
  const float2 pv  = ((const float2*)(pos + (size_t)row  * DD))[lane];
  const float2 nvv = ((const float2*)(x   + (size_t)nidx * DD))[lane];
  float a0 = xv.x - pv.x + 1e-6f, a1 = xv.y - pv.y + 1e-6f;
  float b0 = xv.x - nvv.x + 1e-6f, b1 = xv.y - nvv.y + 1e-6f;
  float dap = a0 * a0 + a1 * a1;
  float dan = b0 * b0 + b1 * b1;
#pragma unroll
  for (int off = 32; off; off >>= 1) {
    dap += __shfl_down(dap, off);
    dan += __shfl_down(dan, off);
  }
  __shared__ float hs[4];
  if (lane == 0) hs[wave] = fmaxf(sqrtf(dap) - sqrtf(dan) + 0.3f, 0.0f);
  __syncthreads();
  if (threadIdx.x == 0) {
    float s = hs[0] + hs[1] + hs[2] + hs[3];
    atomicAdd(&partial[blockIdx.x & (NPART - 1)], s);
  }
}

// Kernel 4: one wave sums the 64 bins -> mean.
__global__ __launch_bounds__(64) void reduce_kernel(const float* __restrict__ partial,
                                                    float* __restrict__ out) {
  float v = partial[threadIdx.x];
#pragma unroll
  for (int off = 32; off; off >>= 1) v += __shfl_down(v, off);
  if (threadIdx.x == 0) out[0] = v * (1.0f / 8192.0f);
}

extern "C" void kernel_launch(void* const* d_in, const int* in_sizes, int n_in,
                              void* d_out, int out_size, void* d_ws, size_t ws_size,
                              hipStream_t stream) {
  const float* x   = (const float*)d_in[0];
  const float* pos = (const float*)d_in[1];
  float* out = (float*)d_out;

  char* w = (char*)d_ws;
  unsigned short* xb = (unsigned short*)w;                       // 2 MB
  float* sq = (float*)(w + (size_t)NN * DD * 2);                 // 32 KB
  float* pscore = (float*)(w + (size_t)NN * DD * 2 + (size_t)NN * 4);  // 2.62 MB
  float* partial = (float*)(w + (size_t)NN * DD * 2 + (size_t)NN * 4 +
                            (size_t)NN * 80 * 4);                // 256 B

  prep_kernel<<<NN / 4, 256, 0, stream>>>(x, xb, sq, partial);
  dist_topk_kernel<<<dim3(NN / 256, CH), 256, 0, stream>>>(xb, sq, pscore);
  final_kernel<<<NN / 4, 256, 0, stream>>>(x, pos, pscore, partial);
  reduce_kernel<<<1, 64, 0, stream>>>(partial, out);
}